// Round 4
// baseline (191.200 us; speedup 1.0000x reference)
//
#include <hip/hip_runtime.h>

#define HID 512
#define SEQ 4096
#define NB 32
#define BS 64
#define NCHUNK (SEQ / BS)   // 64 chunks per batch row
#define CH_STRIDE 514       // [m, den, num[512]]

typedef __attribute__((ext_vector_type(8))) __bf16 bf16x8;
typedef __attribute__((ext_vector_type(16))) float f32x16;

__device__ __forceinline__ float tanh_fast(float v) {
    float e = __expf(2.f * v);
    return 1.f - __fdividef(2.f, e + 1.f);
}

// ---- Kernel 1: W1aT[h][k] = bf16(W1[512+k][h]), coalesced via LDS tile ----
__global__ void transpose_w1a(const float* __restrict__ W1,
                              unsigned short* __restrict__ w1at) {
    __shared__ float tile[64][65];
    int t = threadIdx.x;
    int lane = t & 63;
    int r4 = t >> 6;            // 0..3
    int k0 = blockIdx.x * 64;
    int h0 = blockIdx.y * 64;
#pragma unroll
    for (int i = 0; i < 16; ++i) {
        int r = i * 4 + r4;     // k-row within tile
        tile[r][lane] = W1[(size_t)(HID + k0 + r) * HID + h0 + lane];
    }
    __syncthreads();
#pragma unroll
    for (int i = 0; i < 16; ++i) {
        int hr = i * 4 + r4;    // h-row of output
        __bf16 bv = (__bf16)tile[lane][hr];
        w1at[(size_t)(h0 + hr) * HID + k0 + lane] = *(unsigned short*)&bv;
    }
}

// ---- Kernel 2: pre_part[b][kc][h] = sum_{k in kc-chunk} prev[b][k]*W1_h[k][h] ----
__global__ void pre_partial(const float* __restrict__ prev,
                            const float* __restrict__ W1,
                            float* __restrict__ pre_part) {
    __shared__ float pl[128];
    int kc = blockIdx.x;   // 0..3
    int b  = blockIdx.y;
    int t  = threadIdx.x;
    if (t < 128) pl[t] = prev[b * HID + kc * 128 + t];
    __syncthreads();
    int h0 = 2 * t;
    float ax = 0.f, ay = 0.f;
    for (int k = 0; k < 128; ++k) {
        float pv = pl[k];
        float2 wv = *(const float2*)(W1 + (size_t)(kc * 128 + k) * HID + h0);
        ax += pv * wv.x;
        ay += pv * wv.y;
    }
    float* dst = pre_part + ((size_t)b * 4 + kc) * HID + h0;
    dst[0] = ax; dst[1] = ay;
}

// ---- Kernel 3: fused score GEMM + tanh + w2-reduce + block softmax partials
//      + partial context numerator.  grid (64 chunks, 32 b) x 512.
//      K-loop: static ping-pong prefetch of A-frags (depth 1, no reg arrays). ----
__global__ __launch_bounds__(512, 4)
void score_ctx(const float* __restrict__ ann,
               const unsigned short* __restrict__ w1at,
               const float* __restrict__ pre_part,
               const float* __restrict__ b1,
               const float* __restrict__ W2,
               float* __restrict__ cout) {
    __shared__ unsigned short ann_lds[BS * 512]; // 64 KiB, XOR-swizzled bf16
    __shared__ float pre_lds[512];
    __shared__ float w2_lds[512];
    __shared__ float red[8][64];
    __shared__ float p_lds[64];
    __shared__ float md[2];

    int chunk = blockIdx.x;
    int b = blockIdx.y;
    int s0 = chunk * BS;
    int t = threadIdx.x;
    int w = t >> 6;       // 0..7
    int lane = t & 63;
    int sl = lane & 31;   // M/N lane index within 32
    int g  = lane >> 5;   // k-group (0/1)

    // stage pre_lds = b1 + sum of 4 k-split partials; w2_lds (1 elem/thread)
    {
        float pp = b1[t];
#pragma unroll
        for (int kc = 0; kc < 4; ++kc)
            pp += pre_part[((size_t)b * 4 + kc) * HID + t];
        pre_lds[t] = pp;
        w2_lds[t] = W2[t];
    }

    // stage ann tile (64 rows x 512) -> bf16 LDS, swizzle byte ^= (row&7)<<4
    const float* abase = ann + ((size_t)b * SEQ + s0) * 512;
#pragma unroll
    for (int i = 0; i < 8; ++i) {
        int c = t + i * 512;
        int row = c >> 6;
        int k8 = (c & 63) << 3;
        const float4* src = (const float4*)(abase + (size_t)row * 512 + k8);
        float4 f0 = src[0], f1 = src[1];
        bf16x8 pk;
        pk[0] = (__bf16)f0.x; pk[1] = (__bf16)f0.y;
        pk[2] = (__bf16)f0.z; pk[3] = (__bf16)f0.w;
        pk[4] = (__bf16)f1.x; pk[5] = (__bf16)f1.y;
        pk[6] = (__bf16)f1.z; pk[7] = (__bf16)f1.w;
        unsigned boff = ((unsigned)(row * 512 + k8) * 2u) ^ ((unsigned)(row & 7) << 4);
        *(bf16x8*)((char*)ann_lds + boff) = pk;
    }
    __syncthreads();

    // ---- K-loop: per wave, h-slices [h0, h0+32) and [h0+32, h0+64);
    //      B rows: s rows sl and 32+sl.  Ping-pong A prefetch, static regs. ----
    int h0 = w * 64;
    const unsigned short* wb0 = w1at + (size_t)(h0 + sl) * 512 + g * 8;
    const unsigned short* wb1 = wb0 + 32 * 512;
    unsigned be0 = ((unsigned)(sl * 512 + g * 8)) * 2u;
    unsigned be1 = ((unsigned)((32 + sl) * 512 + g * 8)) * 2u;
    unsigned swz = (unsigned)(sl & 7) << 4;     // (32+sl)&7 == sl&7

    f32x16 acc00, acc01, acc10, acc11;
#pragma unroll
    for (int r = 0; r < 16; ++r) { acc00[r] = 0.f; acc01[r] = 0.f; acc10[r] = 0.f; acc11[r] = 0.f; }

    // prologue: A-frags for ks=0
    bf16x8 pa0 = *(const bf16x8*)(wb0);
    bf16x8 pa1 = *(const bf16x8*)(wb1);
    bf16x8 na0, na1;

#pragma unroll 1
    for (int c = 0; c < 16; ++c) {
        // ---- step A: ks = 2c.  Prefetch ks=2c+1 into n*, compute with pa*. ----
        {
            int kn = 2 * c + 1;
            na0 = *(const bf16x8*)(wb0 + kn * 16);
            na1 = *(const bf16x8*)(wb1 + kn * 16);
            unsigned kb = (unsigned)(2 * c) * 32u;
            bf16x8 b0 = *(const bf16x8*)((const char*)ann_lds + ((be0 + kb) ^ swz));
            bf16x8 b1f = *(const bf16x8*)((const char*)ann_lds + ((be1 + kb) ^ swz));
            acc00 = __builtin_amdgcn_mfma_f32_32x32x16_bf16(pa0, b0, acc00, 0, 0, 0);
            acc01 = __builtin_amdgcn_mfma_f32_32x32x16_bf16(pa0, b1f, acc01, 0, 0, 0);
            acc10 = __builtin_amdgcn_mfma_f32_32x32x16_bf16(pa1, b0, acc10, 0, 0, 0);
            acc11 = __builtin_amdgcn_mfma_f32_32x32x16_bf16(pa1, b1f, acc11, 0, 0, 0);
        }
        // ---- step B: ks = 2c+1.  Prefetch ks=2c+2 into pa*, compute with na*. ----
        {
            int kn = (c < 15) ? (2 * c + 2) : 0;   // wrap harmless
            pa0 = *(const bf16x8*)(wb0 + kn * 16);
            pa1 = *(const bf16x8*)(wb1 + kn * 16);
            unsigned kb = (unsigned)(2 * c + 1) * 32u;
            bf16x8 b0 = *(const bf16x8*)((const char*)ann_lds + ((be0 + kb) ^ swz));
            bf16x8 b1f = *(const bf16x8*)((const char*)ann_lds + ((be1 + kb) ^ swz));
            acc00 = __builtin_amdgcn_mfma_f32_32x32x16_bf16(na0, b0, acc00, 0, 0, 0);
            acc01 = __builtin_amdgcn_mfma_f32_32x32x16_bf16(na0, b1f, acc01, 0, 0, 0);
            acc10 = __builtin_amdgcn_mfma_f32_32x32x16_bf16(na1, b0, acc10, 0, 0, 0);
            acc11 = __builtin_amdgcn_mfma_f32_32x32x16_bf16(na1, b1f, acc11, 0, 0, 0);
        }
    }

    // epilogue: tanh + dot with w2.  acc row r -> h = h0 + crow(r,g) (+32 for slice1),
    // acc col = lane sl -> s rows sl / 32+sl.
    float sp0 = 0.f, sp1 = 0.f;
#pragma unroll
    for (int r = 0; r < 16; ++r) {
        int hl = (r & 3) + 8 * (r >> 2) + 4 * g;
        float pra = pre_lds[h0 + hl],      w2a = w2_lds[h0 + hl];
        float prb = pre_lds[h0 + 32 + hl], w2b = w2_lds[h0 + 32 + hl];
        sp0 += w2a * tanh_fast(acc00[r] + pra) + w2b * tanh_fast(acc10[r] + prb);
        sp1 += w2a * tanh_fast(acc01[r] + pra) + w2b * tanh_fast(acc11[r] + prb);
    }
    // combine the two k-groups (complementary h rows), then cross-wave via LDS
    sp0 += __shfl_xor(sp0, 32);
    sp1 += __shfl_xor(sp1, 32);
    if (lane < 32) {
        red[w][lane]      = sp0;
        red[w][32 + lane] = sp1;
    }
    __syncthreads();

    if (w == 0) {  // wave 0: assemble 64 scores, block-local softmax
        float sc = 0.f;
#pragma unroll
        for (int wv = 0; wv < 8; ++wv) sc += red[wv][lane];
        float m = sc;
#pragma unroll
        for (int off = 32; off; off >>= 1) m = fmaxf(m, __shfl_xor(m, off));
        float p = __expf(sc - m);
        float d = p;
#pragma unroll
        for (int off = 32; off; off >>= 1) d += __shfl_xor(d, off);
        p_lds[lane] = p;
        if (lane == 0) { md[0] = m; md[1] = d; }
    }
    __syncthreads();

    // partial context numerator from the staged bf16 tile (1 col/thread)
    float na = 0.f;
#pragma unroll 8
    for (int s = 0; s < BS; ++s) {
        float pv = p_lds[s];
        unsigned boff = ((unsigned)(s * 512 + t) * 2u) ^ ((unsigned)(s & 7) << 4);
        unsigned short us = *(const unsigned short*)((const char*)ann_lds + boff);
        float av = __uint_as_float((unsigned)us << 16);
        na += pv * av;
    }
    float* cb = cout + (size_t)(b * NCHUNK + chunk) * CH_STRIDE;
    cb[2 + t] = na;
    if (t == 0) { cb[0] = md[0]; cb[1] = md[1]; }
}

// ---- Kernel 4: rescale chunk partials by global max, normalize, write context ----
__global__ void finalize_ctx(const float* __restrict__ cout,
                             float* __restrict__ out) {
    __shared__ float scale[NCHUNK];
    __shared__ float stats[2];
    int b = blockIdx.x;
    int t = threadIdx.x;
    if (t < 64) {
        const float* cb = cout + (size_t)(b * NCHUNK + t) * CH_STRIDE;
        float m = cb[0], d = cb[1];
        float M = m;
#pragma unroll
        for (int off = 32; off; off >>= 1) M = fmaxf(M, __shfl_xor(M, off));
        float sc = __expf(m - M);
        scale[t] = sc;
        float dd = sc * d;
#pragma unroll
        for (int off = 32; off; off >>= 1) dd += __shfl_xor(dd, off);
        if (t == 0) { stats[0] = M; stats[1] = dd; }
    }
    __syncthreads();
    float inv = 1.f / stats[1];
    int a0 = 2 * t;
    float ax = 0.f, ay = 0.f;
    for (int c = 0; c < NCHUNK; ++c) {
        float sc = scale[c];
        const float2 nv = *(const float2*)(cout + (size_t)(b * NCHUNK + c) * CH_STRIDE + 2 + a0);
        ax += sc * nv.x;
        ay += sc * nv.y;
    }
    out[(size_t)b * 512 + a0]     = ax * inv;
    out[(size_t)b * 512 + a0 + 1] = ay * inv;
}

extern "C" void kernel_launch(void* const* d_in, const int* in_sizes, int n_in,
                              void* d_out, int out_size, void* d_ws, size_t ws_size,
                              hipStream_t stream) {
    (void)in_sizes; (void)n_in; (void)out_size; (void)ws_size;
    const float* prev = (const float*)d_in[0];
    const float* ann  = (const float*)d_in[1];
    const float* W1   = (const float*)d_in[2];
    const float* b1   = (const float*)d_in[3];
    const float* W2   = (const float*)d_in[4];
    // b2 (d_in[5]) is a constant shift on scores -> cancels in softmax; unused.
    float* out = (float*)d_out;

    char* ws = (char*)d_ws;
    unsigned short* w1at = (unsigned short*)ws;               // 512*512*2 = 524288 B
    float* pre_part = (float*)(ws + 524288);                  // 32*4*512*4 = 262144 B
    float* cout     = (float*)(ws + 524288 + 262144);         // 32*64*514*4 B

    transpose_w1a<<<dim3(8, 8), dim3(256), 0, stream>>>(W1, w1at);
    pre_partial<<<dim3(4, NB), dim3(256), 0, stream>>>(prev, W1, pre_part);
    score_ctx<<<dim3(NCHUNK, NB), dim3(512), 0, stream>>>(ann, w1at, pre_part, b1, W2, cout);
    finalize_ctx<<<dim3(NB), dim3(256), 0, stream>>>(cout, out);
}

// Round 5
// 143.685 us; speedup vs baseline: 1.3307x; 1.3307x over previous
//
#include <hip/hip_runtime.h>

#define HID 512
#define SEQ 4096
#define NB 32
#define BS 64
#define NCHUNK (SEQ / BS)   // 64 chunks per batch row
#define CH_STRIDE 514       // [m, den, num[512]]

typedef __attribute__((ext_vector_type(8))) __bf16 bf16x8;
typedef __attribute__((ext_vector_type(16))) float f32x16;

__device__ __forceinline__ float tanh_fast(float v) {
    float e = __expf(2.f * v);
    return 1.f - __fdividef(2.f, e + 1.f);
}

// ---- Kernel 1: build W1_a in MFMA-fragment order.
//      frag element (h_tile, ks, lane, j) = W1a[k = ks*16 + (lane>>5)*8 + j]
//                                              [h = h_tile*32 + (lane&31)]
//      offset = ((ht*32 + ks)*64 + lane)*8 + j  (bf16 elems; 16B per lane) ----
__global__ void build_w1af(const float* __restrict__ W1,
                           unsigned short* __restrict__ w1af) {
    __shared__ float tile[64][65];
    int t = threadIdx.x;
    int lane = t & 63;
    int r4 = t >> 6;            // 0..3
    int k0 = blockIdx.x * 64;
    int h0 = blockIdx.y * 64;
#pragma unroll
    for (int i = 0; i < 16; ++i) {
        int r = i * 4 + r4;     // k-row within tile
        tile[r][lane] = W1[(size_t)(HID + k0 + r) * HID + h0 + lane];
    }
    __syncthreads();
#pragma unroll
    for (int i = 0; i < 16; ++i) {
        int hr = i * 4 + r4;    // h-row
        int h = h0 + hr, k = k0 + lane;
        __bf16 bv = (__bf16)tile[lane][hr];
        int ht = h >> 5, hl = h & 31;
        int ks = k >> 4, g = (k >> 3) & 1, j = k & 7;
        size_t off = (((size_t)ht * 32 + ks) * 64 + g * 32 + hl) * 8 + j;
        w1af[off] = *(unsigned short*)&bv;
    }
}

// ---- Kernel 2: pre_part[b][kc][h] = sum_{k in kc-chunk} prev[b][k]*W1_h[k][h] ----
__global__ void pre_partial(const float* __restrict__ prev,
                            const float* __restrict__ W1,
                            float* __restrict__ pre_part) {
    __shared__ float pl[128];
    int kc = blockIdx.x;   // 0..3
    int b  = blockIdx.y;
    int t  = threadIdx.x;
    if (t < 128) pl[t] = prev[b * HID + kc * 128 + t];
    __syncthreads();
    int h0 = 2 * t;
    float ax = 0.f, ay = 0.f;
    for (int k = 0; k < 128; ++k) {
        float pv = pl[k];
        float2 wv = *(const float2*)(W1 + (size_t)(kc * 128 + k) * HID + h0);
        ax += pv * wv.x;
        ay += pv * wv.y;
    }
    float* dst = pre_part + ((size_t)b * 4 + kc) * HID + h0;
    dst[0] = ax; dst[1] = ay;
}

// ---- Kernel 3: fused score GEMM + tanh + w2-reduce + block softmax partials
//      + partial context numerator.  grid (64 chunks, 32 b) x 512.
//      A-frags now COALESCED: one contiguous 1KiB line per load instr. ----
__global__ __launch_bounds__(512, 4)
void score_ctx(const float* __restrict__ ann,
               const unsigned short* __restrict__ w1af,
               const float* __restrict__ pre_part,
               const float* __restrict__ b1,
               const float* __restrict__ W2,
               float* __restrict__ cout) {
    __shared__ unsigned short ann_lds[BS * 512]; // 64 KiB, XOR-swizzled bf16
    __shared__ float pre_lds[512];
    __shared__ float w2_lds[512];
    __shared__ float red[8][64];
    __shared__ float p_lds[64];
    __shared__ float md[2];

    int chunk = blockIdx.x;
    int b = blockIdx.y;
    int s0 = chunk * BS;
    int t = threadIdx.x;
    int w = t >> 6;       // 0..7
    int lane = t & 63;
    int sl = lane & 31;   // M/N lane index within 32
    int g  = lane >> 5;   // k-group (0/1)

    // stage pre_lds = b1 + sum of 4 k-split partials; w2_lds (1 elem/thread)
    {
        float pp = b1[t];
#pragma unroll
        for (int kc = 0; kc < 4; ++kc)
            pp += pre_part[((size_t)b * 4 + kc) * HID + t];
        pre_lds[t] = pp;
        w2_lds[t] = W2[t];
    }

    // stage ann tile (64 rows x 512) -> bf16 LDS, swizzle byte ^= (row&7)<<4
    const float* abase = ann + ((size_t)b * SEQ + s0) * 512;
#pragma unroll
    for (int i = 0; i < 8; ++i) {
        int c = t + i * 512;
        int row = c >> 6;
        int k8 = (c & 63) << 3;
        const float4* src = (const float4*)(abase + (size_t)row * 512 + k8);
        float4 f0 = src[0], f1 = src[1];
        bf16x8 pk;
        pk[0] = (__bf16)f0.x; pk[1] = (__bf16)f0.y;
        pk[2] = (__bf16)f0.z; pk[3] = (__bf16)f0.w;
        pk[4] = (__bf16)f1.x; pk[5] = (__bf16)f1.y;
        pk[6] = (__bf16)f1.z; pk[7] = (__bf16)f1.w;
        unsigned boff = ((unsigned)(row * 512 + k8) * 2u) ^ ((unsigned)(row & 7) << 4);
        *(bf16x8*)((char*)ann_lds + boff) = pk;
    }
    __syncthreads();

    // ---- K-loop: wave w owns h-tiles 2w (h0..h0+31) and 2w+1 (h0+32..h0+63).
    //      A-frag load: contiguous 1KiB per (ht, ks): base + lane*16. ----
    int h0 = w * 64;
    const unsigned short* wb0 = w1af + (size_t)(2 * w) * 16384 + (size_t)lane * 8;
    const unsigned short* wb1 = wb0 + 16384;
    unsigned be0 = ((unsigned)(sl * 512 + g * 8)) * 2u;
    unsigned be1 = ((unsigned)((32 + sl) * 512 + g * 8)) * 2u;
    unsigned swz = (unsigned)(sl & 7) << 4;     // (32+sl)&7 == sl&7

    f32x16 acc00, acc01, acc10, acc11;
#pragma unroll
    for (int r = 0; r < 16; ++r) { acc00[r] = 0.f; acc01[r] = 0.f; acc10[r] = 0.f; acc11[r] = 0.f; }

    // prologue: A-frags for ks=0
    bf16x8 pa0 = *(const bf16x8*)(wb0);
    bf16x8 pa1 = *(const bf16x8*)(wb1);
    bf16x8 na0, na1;

#pragma unroll 1
    for (int c = 0; c < 16; ++c) {
        // ---- step A: ks = 2c.  Prefetch ks=2c+1 into n*, compute with pa*. ----
        {
            int kn = 2 * c + 1;
            na0 = *(const bf16x8*)(wb0 + kn * 512);
            na1 = *(const bf16x8*)(wb1 + kn * 512);
            unsigned kb = (unsigned)(2 * c) * 32u;
            bf16x8 b0 = *(const bf16x8*)((const char*)ann_lds + ((be0 + kb) ^ swz));
            bf16x8 b1f = *(const bf16x8*)((const char*)ann_lds + ((be1 + kb) ^ swz));
            acc00 = __builtin_amdgcn_mfma_f32_32x32x16_bf16(pa0, b0, acc00, 0, 0, 0);
            acc01 = __builtin_amdgcn_mfma_f32_32x32x16_bf16(pa0, b1f, acc01, 0, 0, 0);
            acc10 = __builtin_amdgcn_mfma_f32_32x32x16_bf16(pa1, b0, acc10, 0, 0, 0);
            acc11 = __builtin_amdgcn_mfma_f32_32x32x16_bf16(pa1, b1f, acc11, 0, 0, 0);
        }
        // ---- step B: ks = 2c+1.  Prefetch ks=2c+2 into pa*, compute with na*. ----
        {
            int kn = (c < 15) ? (2 * c + 2) : 0;   // wrap harmless
            pa0 = *(const bf16x8*)(wb0 + kn * 512);
            pa1 = *(const bf16x8*)(wb1 + kn * 512);
            unsigned kb = (unsigned)(2 * c + 1) * 32u;
            bf16x8 b0 = *(const bf16x8*)((const char*)ann_lds + ((be0 + kb) ^ swz));
            bf16x8 b1f = *(const bf16x8*)((const char*)ann_lds + ((be1 + kb) ^ swz));
            acc00 = __builtin_amdgcn_mfma_f32_32x32x16_bf16(na0, b0, acc00, 0, 0, 0);
            acc01 = __builtin_amdgcn_mfma_f32_32x32x16_bf16(na0, b1f, acc01, 0, 0, 0);
            acc10 = __builtin_amdgcn_mfma_f32_32x32x16_bf16(na1, b0, acc10, 0, 0, 0);
            acc11 = __builtin_amdgcn_mfma_f32_32x32x16_bf16(na1, b1f, acc11, 0, 0, 0);
        }
    }

    // epilogue: tanh + dot with w2.  acc row r -> h = h0 + crow(r,g) (+32 for slice1),
    // acc col = lane sl -> s rows sl / 32+sl.
    float sp0 = 0.f, sp1 = 0.f;
#pragma unroll
    for (int r = 0; r < 16; ++r) {
        int hl = (r & 3) + 8 * (r >> 2) + 4 * g;
        float pra = pre_lds[h0 + hl],      w2a = w2_lds[h0 + hl];
        float prb = pre_lds[h0 + 32 + hl], w2b = w2_lds[h0 + 32 + hl];
        sp0 += w2a * tanh_fast(acc00[r] + pra) + w2b * tanh_fast(acc10[r] + prb);
        sp1 += w2a * tanh_fast(acc01[r] + pra) + w2b * tanh_fast(acc11[r] + prb);
    }
    // combine the two k-groups (complementary h rows), then cross-wave via LDS
    sp0 += __shfl_xor(sp0, 32);
    sp1 += __shfl_xor(sp1, 32);
    if (lane < 32) {
        red[w][lane]      = sp0;
        red[w][32 + lane] = sp1;
    }
    __syncthreads();

    if (w == 0) {  // wave 0: assemble 64 scores, block-local softmax
        float sc = 0.f;
#pragma unroll
        for (int wv = 0; wv < 8; ++wv) sc += red[wv][lane];
        float m = sc;
#pragma unroll
        for (int off = 32; off; off >>= 1) m = fmaxf(m, __shfl_xor(m, off));
        float p = __expf(sc - m);
        float d = p;
#pragma unroll
        for (int off = 32; off; off >>= 1) d += __shfl_xor(d, off);
        p_lds[lane] = p;
        if (lane == 0) { md[0] = m; md[1] = d; }
    }
    __syncthreads();

    // partial context numerator from the staged bf16 tile (1 col/thread)
    float na = 0.f;
#pragma unroll 8
    for (int s = 0; s < BS; ++s) {
        float pv = p_lds[s];
        unsigned boff = ((unsigned)(s * 512 + t) * 2u) ^ ((unsigned)(s & 7) << 4);
        unsigned short us = *(const unsigned short*)((const char*)ann_lds + boff);
        float av = __uint_as_float((unsigned)us << 16);
        na += pv * av;
    }
    float* cb = cout + (size_t)(b * NCHUNK + chunk) * CH_STRIDE;
    cb[2 + t] = na;
    if (t == 0) { cb[0] = md[0]; cb[1] = md[1]; }
}

// ---- Kernel 4: rescale chunk partials by global max, normalize, write context ----
__global__ void finalize_ctx(const float* __restrict__ cout,
                             float* __restrict__ out) {
    __shared__ float scale[NCHUNK];
    __shared__ float stats[2];
    int b = blockIdx.x;
    int t = threadIdx.x;
    if (t < 64) {
        const float* cb = cout + (size_t)(b * NCHUNK + t) * CH_STRIDE;
        float m = cb[0], d = cb[1];
        float M = m;
#pragma unroll
        for (int off = 32; off; off >>= 1) M = fmaxf(M, __shfl_xor(M, off));
        float sc = __expf(m - M);
        scale[t] = sc;
        float dd = sc * d;
#pragma unroll
        for (int off = 32; off; off >>= 1) dd += __shfl_xor(dd, off);
        if (t == 0) { stats[0] = M; stats[1] = dd; }
    }
    __syncthreads();
    float inv = 1.f / stats[1];
    int a0 = 2 * t;
    float ax = 0.f, ay = 0.f;
    for (int c = 0; c < NCHUNK; ++c) {
        float sc = scale[c];
        const float2 nv = *(const float2*)(cout + (size_t)(b * NCHUNK + c) * CH_STRIDE + 2 + a0);
        ax += sc * nv.x;
        ay += sc * nv.y;
    }
    out[(size_t)b * 512 + a0]     = ax * inv;
    out[(size_t)b * 512 + a0 + 1] = ay * inv;
}

extern "C" void kernel_launch(void* const* d_in, const int* in_sizes, int n_in,
                              void* d_out, int out_size, void* d_ws, size_t ws_size,
                              hipStream_t stream) {
    (void)in_sizes; (void)n_in; (void)out_size; (void)ws_size;
    const float* prev = (const float*)d_in[0];
    const float* ann  = (const float*)d_in[1];
    const float* W1   = (const float*)d_in[2];
    const float* b1   = (const float*)d_in[3];
    const float* W2   = (const float*)d_in[4];
    // b2 (d_in[5]) is a constant shift on scores -> cancels in softmax; unused.
    float* out = (float*)d_out;

    char* ws = (char*)d_ws;
    unsigned short* w1af = (unsigned short*)ws;               // 512*512*2 = 524288 B
    float* pre_part = (float*)(ws + 524288);                  // 32*4*512*4 = 262144 B
    float* cout     = (float*)(ws + 524288 + 262144);         // 32*64*514*4 B

    build_w1af<<<dim3(8, 8), dim3(256), 0, stream>>>(W1, w1af);
    pre_partial<<<dim3(4, NB), dim3(256), 0, stream>>>(prev, W1, pre_part);
    score_ctx<<<dim3(NCHUNK, NB), dim3(512), 0, stream>>>(ann, w1af, pre_part, b1, W2, cout);
    finalize_ctx<<<dim3(NB), dim3(256), 0, stream>>>(cout, out);
}